// Round 7
// baseline (354.715 us; speedup 1.0000x reference)
//
#include <hip/hip_runtime.h>
#include <hip/hip_bf16.h>
#include <stdint.h>

// Problem constants
#define Bq 1024
#define Dq 512
#define Nq 16
#define Hq 512
#define Mq (Bq*Nq)   // 16384

typedef short v8s  __attribute__((ext_vector_type(8)));
typedef float v4f  __attribute__((ext_vector_type(4)));
typedef float v16f __attribute__((ext_vector_type(16)));

typedef __attribute__((address_space(3))) unsigned int as3_u32;
typedef __attribute__((address_space(1))) const unsigned int as1_u32;

#define VMCNT(n) asm volatile("s_waitcnt vmcnt(" #n ")" ::: "memory")

__device__ __forceinline__ unsigned short f2bf(float f) {
  union { float f; unsigned u; } v; v.f = f;
  return (unsigned short)((v.u + 0x7fffu + ((v.u >> 16) & 1u)) >> 16);
}

// Xb[b*16+n][d] = bf16(x[b][d][n])
__global__ void k_transpose_x(const float* __restrict__ x, unsigned short* __restrict__ xb) {
  __shared__ float lds[Dq][Nq + 1];
  const int b = blockIdx.x;
  const float* xi = x + (size_t)b * Dq * Nq;
  const int t = threadIdx.x;
  for (int p = 0; p < (Dq*Nq)/256; ++p) {
    int i = t + p*256;
    lds[i >> 4][i & (Nq-1)] = xi[i];
  }
  __syncthreads();
  unsigned short* o = xb + (size_t)b * Nq * Dq;
  for (int p = 0; p < (Dq*Nq)/256; ++p) {
    int i = t + p*256;
    o[i] = f2bf(lds[i & (Dq-1)][i >> 9]);   // i = n*512 + d
  }
}

// One dispatch for all weight transposes: z=0 -> Ws1, z=1 -> Ws2, z>=2 -> Wc1[z-2]
__global__ void k_transpose_w(const float* __restrict__ Ws1, const float* __restrict__ Ws2,
                              const float* __restrict__ Wc1,
                              unsigned short* __restrict__ Ws1t, unsigned short* __restrict__ Ws2t,
                              unsigned short* __restrict__ Wc1t) {
  __shared__ float tile[32][33];
  const int z = blockIdx.z;
  const float* in;
  unsigned short* out;
  if (z == 0)      { in = Ws1; out = Ws1t; }
  else if (z == 1) { in = Ws2; out = Ws2t; }
  else             { in = Wc1 + (size_t)(z-2) * 512 * 512; out = Wc1t + (size_t)(z-2) * 512 * 512; }
  const int tx = threadIdx.x, ty = threadIdx.y;  // (32,8)
  const int c0 = blockIdx.x * 32, r0 = blockIdx.y * 32;
#pragma unroll
  for (int j = 0; j < 4; ++j)
    tile[ty + j*8][tx] = in[(size_t)(r0 + ty + j*8) * 512 + c0 + tx];
  __syncthreads();
#pragma unroll
  for (int j = 0; j < 4; ++j) {
    int c = c0 + ty + j*8;   // output row (input col)
    int r = r0 + tx;         // output col (input row)
    out[(size_t)c * 512 + r] = f2bf(tile[tx][ty + j*8]);
  }
}

// ---------------------------------------------------------------------------
// Old-structure GEMM, kept for the two shared-MLP GEMMs (MODE=0 only).
// ---------------------------------------------------------------------------
template<int MODE, int BM>
__global__ __launch_bounds__(256, 2)
void k_gemm(const unsigned short* __restrict__ A,
            const unsigned short* __restrict__ Bt,
            const float* __restrict__ bias,
            void* __restrict__ out_,
            const float* __restrict__ w2,
            int permute) {
  constexpr int BN = 128, BK = 32, KD = 512;
  constexpr int NI = (BM == 256) ? 4 : 2;
  constexpr int AG = BM / 16;
  constexpr int TG = AG + BN / 16;
  __shared__ __align__(16) unsigned short As[2][BM][BK];
  __shared__ __align__(16) unsigned short Bs[2][BN][BK];

  const int t = threadIdx.x;
  const int wave = t >> 6, lane = t & 63;
  const int wr = (BM == 256) ? wave : (wave >> 1);
  const int wc = (BM == 256) ? 0    : (wave & 1);
  const int l32 = lane & 31, kh0 = lane >> 5;
  const int bm = blockIdx.x * BM, bn = blockIdx.y * BN;
  const int z = blockIdx.z;

  const unsigned short* Bz = Bt + (size_t)z * KD * 512;
  const float* biasz = bias + (size_t)z * 512;

  const int lrow = lane >> 2;
  const int lslot = lane & 3;

  auto stage = [&](int buf, int kt) {
#pragma unroll
    for (int i = wave; i < TG; i += 4) {
      const int isA = (i < AG);
      const int r0 = (isA ? i : i - AG) * 16;
      const int row = r0 + lrow;
      const int cg = lslot ^ ((row >> 1) & 3);
      const unsigned short* g = isA ? &A [(size_t)(bm + row) * KD + kt*BK + cg*8]
                                    : &Bz[(size_t)(bn + row) * KD + kt*BK + cg*8];
      as3_u32* d = isA ? (as3_u32*)&As[buf][r0][0] : (as3_u32*)&Bs[buf][r0][0];
      __builtin_amdgcn_global_load_lds((as1_u32*)g, d, 16, 0, 0);
    }
  };

  v16f acc[2][NI] = {};

  stage(0, 0);
  __syncthreads();

  for (int kt = 0; kt < KD / BK; ++kt) {
    const int cur = kt & 1;
    if (kt + 1 < KD / BK) stage(cur ^ 1, kt + 1);

    v8s af[2][2], bf[NI][2];
#pragma unroll
    for (int mi = 0; mi < 2; ++mi) {
      int ra = wr*64 + mi*32 + l32;
#pragma unroll
      for (int kh = 0; kh < 2; ++kh) {
        int c = kh*2 + kh0;
        af[mi][kh] = *(const v8s*)&As[cur][ra][(c ^ ((ra >> 1) & 3)) * 8];
      }
    }
#pragma unroll
    for (int ni = 0; ni < NI; ++ni) {
      int rb = wc*64 + ni*32 + l32;
#pragma unroll
      for (int kh = 0; kh < 2; ++kh) {
        int c = kh*2 + kh0;
        bf[ni][kh] = *(const v8s*)&Bs[cur][rb][(c ^ ((rb >> 1) & 3)) * 8];
      }
    }
#pragma unroll
    for (int kh = 0; kh < 2; ++kh)
#pragma unroll
      for (int mi = 0; mi < 2; ++mi)
#pragma unroll
        for (int ni = 0; ni < NI; ++ni)
          acc[mi][ni] = __builtin_amdgcn_mfma_f32_32x32x16_bf16(af[mi][kh], bf[ni][kh], acc[mi][ni], 0, 0, 0);
    __syncthreads();
  }

  if (MODE == 0) {
    unsigned short* O = (unsigned short*)out_;
#pragma unroll
    for (int mi = 0; mi < 2; ++mi) {
#pragma unroll
      for (int ni = 0; ni < NI; ++ni) {
        int col = bn + wc*64 + ni*32 + l32;
        float bcol = biasz[col];
#pragma unroll
        for (int reg = 0; reg < 16; ++reg) {
          int rl = (reg & 3) + 8*(reg >> 2) + 4*kh0;
          int grow = bm + wr*64 + mi*32 + rl;
          int orow = permute ? ((grow & 15) * Bq + (grow >> 4)) : grow;
          float v = acc[mi][ni][reg] + bcol;
          v = v >= 0.f ? v : 0.1f * v;
          O[(size_t)orow * 512 + col] = f2bf(v);
        }
      }
    }
  } else {
    float* FL = (float*)out_;
    const float* w2z = w2 + (size_t)z * 512;
#pragma unroll
    for (int mi = 0; mi < 2; ++mi) {
#pragma unroll
      for (int reg = 0; reg < 16; ++reg) {
        int rl = (reg & 3) + 8*(reg >> 2) + 4*kh0;
        float s = 0.f;
#pragma unroll
        for (int ni = 0; ni < NI; ++ni) {
          int col = bn + ni*32 + l32;
          float v = acc[mi][ni][reg] + biasz[col];
          v = v >= 0.f ? v : 0.1f * v;
          s += v * w2z[col];
        }
#pragma unroll
        for (int off = 1; off < 32; off <<= 1)
          s += __shfl_xor(s, off, 64);
        if (l32 == 0) {
          int grow = bm + wave*64 + mi*32 + rl;
          atomicAdd(&FL[(size_t)grow * Nq + z], s);
        }
      }
    }
  }
}

// ---------------------------------------------------------------------------
// Head-GEMM v6b: ring-4 deep-prefetch pipeline (resubmit of v6; R6 bench was
// an infra failure with no counters, kernel unchanged -- only the risky
// k_prep merge reverted to the R5-proven transpose kernels).
// 256x256 tile, 512 threads = 8 waves (2M x 4N), per-wave 128x64 output via
// 16x16x32 MFMA (acc[8][4] v4f = 128 regs).  BK=32, 16 K-tiles; LDS = 4 ring
// slots x (A 16K + B 16K) = 128 KiB.  Tile T reads slot T&3 while staging
// tile T+3 into slot (T+3)&3 -- disjoint from slots T,T+1,T+2 by construction
// (race-free: slot (T-1)&3 is reused only after the barrier that closes
// iteration T-1's reads).  One VMCNT(4) per tile awaits a tile issued ~2 full
// tile-phases (~800+ cyc) earlier -> covers HBM/L2 latency (the cover all
// prior 26-30% variants lacked).  32-MFMA cluster per tile between 2 raw
// barriers, setprio around the cluster.  Fragment math / swizzle / epilogue
// verbatim from the harness-passed R2 kernel (zero-conflict 16x16 class).
// ---------------------------------------------------------------------------
__global__ __launch_bounds__(512, 1)
void k_headgemm(const unsigned short* __restrict__ A,
                const unsigned short* __restrict__ Bt,
                const float* __restrict__ bias,
                float* __restrict__ FL,
                const float* __restrict__ w2) {
  __shared__ __align__(16) unsigned short As[4][256][32];
  __shared__ __align__(16) unsigned short Bs[4][256][32];

  const int t = threadIdx.x;
  const int wave = t >> 6, lane = t & 63;
  const int wr = wave >> 2, wc = wave & 3;         // 2M x 4N of 128x64
  const int fr = lane & 15, fq = lane >> 4;

  const int bm = blockIdx.x * 256;                 // natural order (R3 lesson)
  const int bn = blockIdx.y * 256;
  const int z  = blockIdx.z;

  const unsigned short* Bz = Bt + (size_t)z * Dq * 512;
  const float* biasz = bias + (size_t)z * 512;
  const float* w2z   = w2   + (size_t)z * 512;

  // Staging: per tile, A = 256 rows x 32 cols (16 KB) = 2 issues of 8 KB
  // (128 rows each); same for B.  Thread t -> row t>>2, chunk (t&3) pre-XORed
  // with the read-side swizzle ((row>>1)&3); gload_lds dest is linear.
  const int srow = t >> 2;                         // 0..127 within issue group
  const int schunk = (t & 3) ^ ((t >> 3) & 3);
  const unsigned short* aS = A  + (size_t)(bm + srow) * Dq + schunk*8;
  const unsigned short* bS = Bz + (size_t)(bn + srow) * Dq + schunk*8;

  auto stageT = [&](int T) {
    const int s = T & 3;
#pragma unroll
    for (int j = 0; j < 2; ++j) {
      __builtin_amdgcn_global_load_lds((as1_u32*)(aS + (size_t)j*128*Dq + T*32),
                                       (as3_u32*)&As[s][j*128 + wave*16][0], 16, 0, 0);
      __builtin_amdgcn_global_load_lds((as1_u32*)(bS + (size_t)j*128*Dq + T*32),
                                       (as3_u32*)&Bs[s][j*128 + wave*16][0], 16, 0, 0);
    }
  };

  // Fragment byte offsets within one [256][32] slot (R2-verified formula):
  // row r, lane chunk fq -> LDS chunk fq ^ ((r>>1)&3); (r>>1)&3 == (fr>>1)&3.
  const int swz = (fq ^ ((fr >> 1) & 3)) * 16;
  int offA[8], offB[4];
#pragma unroll
  for (int mi = 0; mi < 8; ++mi) offA[mi] = (wr*128 + mi*16 + fr) * 64 + swz;
#pragma unroll
  for (int ni = 0; ni < 4; ++ni) offB[ni] = (wc*64  + ni*16 + fr) * 64 + swz;

  v4f acc[8][4] = {};

  // Prologue: stage tiles 0,1,2 (12 loads/thread); await tiles 0,1.
  stageT(0); stageT(1); stageT(2);
  VMCNT(4);
  __builtin_amdgcn_s_barrier();
  __builtin_amdgcn_sched_barrier(0);

#pragma unroll 4
  for (int T = 0; T < 16; ++T) {
    const char* aB = (const char*)&As[T & 3][0][0];
    const char* bB = (const char*)&Bs[T & 3][0][0];
    v8s af[8], bf[4];
#pragma unroll
    for (int mi = 0; mi < 8; ++mi) af[mi] = *(const v8s*)(aB + offA[mi]);
#pragma unroll
    for (int ni = 0; ni < 4; ++ni) bf[ni] = *(const v8s*)(bB + offB[ni]);

    if (T + 3 < 16) stageT(T + 3);   // slot (T+3)&3: disjoint from T..T+2

    __builtin_amdgcn_s_barrier();

    __builtin_amdgcn_s_setprio(1);
#pragma unroll
    for (int mi = 0; mi < 8; ++mi)
#pragma unroll
      for (int ni = 0; ni < 4; ++ni)
        acc[mi][ni] = __builtin_amdgcn_mfma_f32_16x16x32_bf16(af[mi], bf[ni], acc[mi][ni], 0, 0, 0);
    __builtin_amdgcn_s_setprio(0);

    // Await tile T+2 (issued during tile T-1): keep 4 loads in flight.
    if (T < 14)       { VMCNT(4); }
    else if (T == 14) { VMCNT(0); }
    __builtin_amdgcn_s_barrier();
    __builtin_amdgcn_sched_barrier(0);
  }

  // Epilogue (verbatim R2): lrelu + Wc2 dot over wave's 64 cols, 16-lane
  // reduce, atomicAdd into FL[m][z].  D-frag: col=l&15, row=(l>>4)*4+reg.
  float bcol[4], wcol[4];
#pragma unroll
  for (int ni = 0; ni < 4; ++ni) {
    int col = bn + wc*64 + ni*16 + fr;
    bcol[ni] = biasz[col];
    wcol[ni] = w2z[col];
  }
#pragma unroll
  for (int mi = 0; mi < 8; ++mi) {
#pragma unroll
    for (int reg = 0; reg < 4; ++reg) {
      float s = 0.f;
#pragma unroll
      for (int ni = 0; ni < 4; ++ni) {
        float v = acc[mi][ni][reg] + bcol[ni];
        v = v >= 0.f ? v : 0.1f * v;
        s += v * wcol[ni];
      }
#pragma unroll
      for (int off = 1; off < 16; off <<= 1)
        s += __shfl_xor(s, off, 64);
      if (fr == 0) {
        int grow = bm + wr*128 + mi*16 + fq*4 + reg;
        atomicAdd(&FL[(size_t)grow * Nq + z], s);
      }
    }
  }
}

// full_out[m][n] = FL[m][n] + bc2[n]; out[b][n] = sigmoid(full_out[n*B+b][n])
__global__ void k_final(const float* __restrict__ fl, const float* __restrict__ bc2,
                        float* __restrict__ out) {
  int i = blockIdx.x * 256 + threadIdx.x;
  int m = i >> 4, n = i & 15;
  float v = fl[i] + bc2[n];
  out[Mq + i] = v;
  if (n == (m >> 10)) {
    int b = m & (Bq - 1);
    out[b * Nq + n] = 1.f / (1.f + __expf(-v));
  }
}

extern "C" void kernel_launch(void* const* d_in, const int* in_sizes, int n_in,
                              void* d_out, int out_size, void* d_ws, size_t ws_size,
                              hipStream_t stream) {
  (void)in_sizes; (void)n_in; (void)out_size; (void)ws_size;
  const float* x   = (const float*)d_in[0];
  const float* Ws1 = (const float*)d_in[1];
  const float* bs1 = (const float*)d_in[2];
  const float* Ws2 = (const float*)d_in[3];
  const float* bs2 = (const float*)d_in[4];
  const float* Wc1 = (const float*)d_in[5];
  const float* bc1 = (const float*)d_in[6];
  const float* Wc2 = (const float*)d_in[7];
  const float* bc2 = (const float*)d_in[8];

  char* ws = (char*)d_ws;
  unsigned short* Xb   = (unsigned short*)(ws);
  unsigned short* Hbuf = (unsigned short*)(ws + (size_t)16*1024*1024);
  unsigned short* Sm   = (unsigned short*)(ws + (size_t)32*1024*1024);
  unsigned short* Ws1t = (unsigned short*)(ws + (size_t)48*1024*1024);
  unsigned short* Ws2t = (unsigned short*)(ws + (size_t)48*1024*1024 + 512*1024);
  unsigned short* Wc1t = (unsigned short*)(ws + (size_t)49*1024*1024);
  float*          FL   = (float*)         (ws + (size_t)57*1024*1024);

  hipMemsetAsync(FL, 0, (size_t)Mq * Nq * sizeof(float), stream);

  k_transpose_x<<<Bq, 256, 0, stream>>>(x, Xb);
  k_transpose_w<<<dim3(16,16,18), dim3(32,8), 0, stream>>>(Ws1, Ws2, Wc1, Ws1t, Ws2t, Wc1t);

  // shared MLP: H = lrelu(Xb@Ws1+bs1); Sm = lrelu(H@Ws2+bs2) in m = n*B+b row order
  k_gemm<0,128><<<dim3(128,4,1), 256, 0, stream>>>(Xb,   Ws1t, bs1, Hbuf, nullptr, 0);
  k_gemm<0,128><<<dim3(128,4,1), 256, 0, stream>>>(Hbuf, Ws2t, bs2, Sm,   nullptr, 1);
  // fused per-head GEMM + H-reduction into FL (ring-4 deep prefetch)
  k_headgemm<<<dim3(64,2,16), 512, 0, stream>>>(Sm, Wc1t, bc1, FL, Wc2);

  k_final<<<(Mq*Nq)/256, 256, 0, stream>>>(FL, bc2, (float*)d_out);
}

// Round 8
// 323.492 us; speedup vs baseline: 1.0965x; 1.0965x over previous
//
#include <hip/hip_runtime.h>
#include <hip/hip_bf16.h>
#include <stdint.h>

// Problem constants
#define Bq 1024
#define Dq 512
#define Nq 16
#define Hq 512
#define Mq (Bq*Nq)   // 16384

typedef short v8s  __attribute__((ext_vector_type(8)));
typedef float v4f  __attribute__((ext_vector_type(4)));
typedef float v16f __attribute__((ext_vector_type(16)));

typedef __attribute__((address_space(3))) unsigned int as3_u32;
typedef __attribute__((address_space(1))) const unsigned int as1_u32;

__device__ __forceinline__ unsigned short f2bf(float f) {
  union { float f; unsigned u; } v; v.f = f;
  return (unsigned short)((v.u + 0x7fffu + ((v.u >> 16) & 1u)) >> 16);
}

// Xb[b*16+n][d] = bf16(x[b][d][n])
__global__ void k_transpose_x(const float* __restrict__ x, unsigned short* __restrict__ xb) {
  __shared__ float lds[Dq][Nq + 1];
  const int b = blockIdx.x;
  const float* xi = x + (size_t)b * Dq * Nq;
  const int t = threadIdx.x;
  for (int p = 0; p < (Dq*Nq)/256; ++p) {
    int i = t + p*256;
    lds[i >> 4][i & (Nq-1)] = xi[i];
  }
  __syncthreads();
  unsigned short* o = xb + (size_t)b * Nq * Dq;
  for (int p = 0; p < (Dq*Nq)/256; ++p) {
    int i = t + p*256;
    o[i] = f2bf(lds[i & (Dq-1)][i >> 9]);   // i = n*512 + d
  }
}

// One dispatch for all weight transposes: z=0 -> Ws1, z=1 -> Ws2, z>=2 -> Wc1[z-2]
__global__ void k_transpose_w(const float* __restrict__ Ws1, const float* __restrict__ Ws2,
                              const float* __restrict__ Wc1,
                              unsigned short* __restrict__ Ws1t, unsigned short* __restrict__ Ws2t,
                              unsigned short* __restrict__ Wc1t) {
  __shared__ float tile[32][33];
  const int z = blockIdx.z;
  const float* in;
  unsigned short* out;
  if (z == 0)      { in = Ws1; out = Ws1t; }
  else if (z == 1) { in = Ws2; out = Ws2t; }
  else             { in = Wc1 + (size_t)(z-2) * 512 * 512; out = Wc1t + (size_t)(z-2) * 512 * 512; }
  const int tx = threadIdx.x, ty = threadIdx.y;  // (32,8)
  const int c0 = blockIdx.x * 32, r0 = blockIdx.y * 32;
#pragma unroll
  for (int j = 0; j < 4; ++j)
    tile[ty + j*8][tx] = in[(size_t)(r0 + ty + j*8) * 512 + c0 + tx];
  __syncthreads();
#pragma unroll
  for (int j = 0; j < 4; ++j) {
    int c = c0 + ty + j*8;   // output row (input col)
    int r = r0 + tx;         // output col (input row)
    out[(size_t)c * 512 + r] = f2bf(tile[tx][ty + j*8]);
  }
}

// ---------------------------------------------------------------------------
// Old-structure GEMM, kept for the two shared-MLP GEMMs (MODE=0 only).
// ---------------------------------------------------------------------------
template<int MODE, int BM>
__global__ __launch_bounds__(256, 2)
void k_gemm(const unsigned short* __restrict__ A,
            const unsigned short* __restrict__ Bt,
            const float* __restrict__ bias,
            void* __restrict__ out_,
            const float* __restrict__ w2,
            int permute) {
  constexpr int BN = 128, BK = 32, KD = 512;
  constexpr int NI = (BM == 256) ? 4 : 2;
  constexpr int AG = BM / 16;
  constexpr int TG = AG + BN / 16;
  __shared__ __align__(16) unsigned short As[2][BM][BK];
  __shared__ __align__(16) unsigned short Bs[2][BN][BK];

  const int t = threadIdx.x;
  const int wave = t >> 6, lane = t & 63;
  const int wr = (BM == 256) ? wave : (wave >> 1);
  const int wc = (BM == 256) ? 0    : (wave & 1);
  const int l32 = lane & 31, kh0 = lane >> 5;
  const int bm = blockIdx.x * BM, bn = blockIdx.y * BN;
  const int z = blockIdx.z;

  const unsigned short* Bz = Bt + (size_t)z * KD * 512;
  const float* biasz = bias + (size_t)z * 512;

  const int lrow = lane >> 2;
  const int lslot = lane & 3;

  auto stage = [&](int buf, int kt) {
#pragma unroll
    for (int i = wave; i < TG; i += 4) {
      const int isA = (i < AG);
      const int r0 = (isA ? i : i - AG) * 16;
      const int row = r0 + lrow;
      const int cg = lslot ^ ((row >> 1) & 3);
      const unsigned short* g = isA ? &A [(size_t)(bm + row) * KD + kt*BK + cg*8]
                                    : &Bz[(size_t)(bn + row) * KD + kt*BK + cg*8];
      as3_u32* d = isA ? (as3_u32*)&As[buf][r0][0] : (as3_u32*)&Bs[buf][r0][0];
      __builtin_amdgcn_global_load_lds((as1_u32*)g, d, 16, 0, 0);
    }
  };

  v16f acc[2][NI] = {};

  stage(0, 0);
  __syncthreads();

  for (int kt = 0; kt < KD / BK; ++kt) {
    const int cur = kt & 1;
    if (kt + 1 < KD / BK) stage(cur ^ 1, kt + 1);

    v8s af[2][2], bf[NI][2];
#pragma unroll
    for (int mi = 0; mi < 2; ++mi) {
      int ra = wr*64 + mi*32 + l32;
#pragma unroll
      for (int kh = 0; kh < 2; ++kh) {
        int c = kh*2 + kh0;
        af[mi][kh] = *(const v8s*)&As[cur][ra][(c ^ ((ra >> 1) & 3)) * 8];
      }
    }
#pragma unroll
    for (int ni = 0; ni < NI; ++ni) {
      int rb = wc*64 + ni*32 + l32;
#pragma unroll
      for (int kh = 0; kh < 2; ++kh) {
        int c = kh*2 + kh0;
        bf[ni][kh] = *(const v8s*)&Bs[cur][rb][(c ^ ((rb >> 1) & 3)) * 8];
      }
    }
#pragma unroll
    for (int kh = 0; kh < 2; ++kh)
#pragma unroll
      for (int mi = 0; mi < 2; ++mi)
#pragma unroll
        for (int ni = 0; ni < NI; ++ni)
          acc[mi][ni] = __builtin_amdgcn_mfma_f32_32x32x16_bf16(af[mi][kh], bf[ni][kh], acc[mi][ni], 0, 0, 0);
    __syncthreads();
  }

  if (MODE == 0) {
    unsigned short* O = (unsigned short*)out_;
#pragma unroll
    for (int mi = 0; mi < 2; ++mi) {
#pragma unroll
      for (int ni = 0; ni < NI; ++ni) {
        int col = bn + wc*64 + ni*32 + l32;
        float bcol = biasz[col];
#pragma unroll
        for (int reg = 0; reg < 16; ++reg) {
          int rl = (reg & 3) + 8*(reg >> 2) + 4*kh0;
          int grow = bm + wr*64 + mi*32 + rl;
          int orow = permute ? ((grow & 15) * Bq + (grow >> 4)) : grow;
          float v = acc[mi][ni][reg] + bcol;
          v = v >= 0.f ? v : 0.1f * v;
          O[(size_t)orow * 512 + col] = f2bf(v);
        }
      }
    }
  } else {
    float* FL = (float*)out_;
    const float* w2z = w2 + (size_t)z * 512;
#pragma unroll
    for (int mi = 0; mi < 2; ++mi) {
#pragma unroll
      for (int reg = 0; reg < 16; ++reg) {
        int rl = (reg & 3) + 8*(reg >> 2) + 4*kh0;
        float s = 0.f;
#pragma unroll
        for (int ni = 0; ni < NI; ++ni) {
          int col = bn + ni*32 + l32;
          float v = acc[mi][ni][reg] + biasz[col];
          v = v >= 0.f ? v : 0.1f * v;
          s += v * w2z[col];
        }
#pragma unroll
        for (int off = 1; off < 32; off <<= 1)
          s += __shfl_xor(s, off, 64);
        if (l32 == 0) {
          int grow = bm + wave*64 + mi*32 + rl;
          atomicAdd(&FL[(size_t)grow * Nq + z], s);
        }
      }
    }
  }
}

// ---------------------------------------------------------------------------
// Head-GEMM v8: R5 (best, 207us @ 29.8% MfmaUtil) + double-buffering.
// 128x128 tile, 256 threads = 4 waves of 64x64, 16x16x32 MFMA, acc[4][4] v4f.
// BK=32, DOUBLE-buffered LDS As/Bs[2][128][32] = 32 KiB (-> ~3 blocks/CU,
// 12 waves/CU: the cross-block overlap regime that beats every 1-block/CU
// schedule variant measured this session).  stage(kt+1) is issued BEFORE
// kt's ds_reads/MFMA, so the end-of-step __syncthreads drain targets loads
// already ~300-400 cyc in flight (R5 drained immediately after issue -- the
// only structural flaw left in it).  One barrier per K-step.  Fragment math,
// zero-conflict chunk-XOR swizzle, staging lane math, epilogue: all verbatim
// from harness-passed R2/R5 kernels.  No setprio/sched_barrier/counted-vmcnt
// (falsified R1/R2/R7).  Natural dispatch order (R3 lesson).
// ---------------------------------------------------------------------------
__global__ __launch_bounds__(256, 3)
void k_headgemm(const unsigned short* __restrict__ A,
                const unsigned short* __restrict__ Bt,
                const float* __restrict__ bias,
                float* __restrict__ FL,
                const float* __restrict__ w2) {
  __shared__ __align__(16) unsigned short As[2][128][32];
  __shared__ __align__(16) unsigned short Bs[2][128][32];

  const int t = threadIdx.x;
  const int wave = t >> 6, lane = t & 63;
  const int wr = wave >> 1, wc = wave & 1;         // 2x2 waves of 64x64
  const int fr = lane & 15, fq = lane >> 4;

  const int bm = blockIdx.x * 128;
  const int bn = blockIdx.y * 128;
  const int z  = blockIdx.z;

  const unsigned short* Bz = Bt + (size_t)z * Dq * 512;
  const float* biasz = bias + (size_t)z * 512;
  const float* w2z   = w2   + (size_t)z * 512;

  // Staging (R2-verified lane math for [*][32] rows): per K-tile each wave
  // stages A rows [wave*32,+32) and B rows [wave*32,+32) as 2+2 issues of
  // 1 KB (16 rows x 64 B).  Lane l -> row l>>2, 16B slot l&3; source chunk
  // pre-XORed with the read-side swizzle ((row>>1)&3).
  const int sr = lane >> 2;
  const int sc = (lane & 3) ^ ((sr >> 1) & 3);
  const unsigned short* aSrc = A  + (size_t)(bm + wave*32 + sr) * Dq + sc*8;
  const unsigned short* bSrc = Bz + (size_t)(bn + wave*32 + sr) * Dq + sc*8;

  auto stage = [&](int buf, int kt) {
#pragma unroll
    for (int j = 0; j < 2; ++j) {
      __builtin_amdgcn_global_load_lds((as1_u32*)(aSrc + kt*32 + (size_t)j*16*Dq),
                                       (as3_u32*)&As[buf][wave*32 + j*16][0], 16, 0, 0);
      __builtin_amdgcn_global_load_lds((as1_u32*)(bSrc + kt*32 + (size_t)j*16*Dq),
                                       (as3_u32*)&Bs[buf][wave*32 + j*16][0], 16, 0, 0);
    }
  };

  // Fragment byte offsets within one [128][32] buffer (R2/R5-verified):
  // row r, lane chunk fq -> LDS chunk fq ^ ((r>>1)&3); (r>>1)&3 == (fr>>1)&3.
  const int swz = (fq ^ ((fr >> 1) & 3)) * 16;
  int offA[4], offB[4];
#pragma unroll
  for (int mi = 0; mi < 4; ++mi) offA[mi] = (wr*64 + mi*16 + fr) * 64 + swz;
#pragma unroll
  for (int ni = 0; ni < 4; ++ni) offB[ni] = (wc*64 + ni*16 + fr) * 64 + swz;

  v4f acc[4][4] = {};

  stage(0, 0);
  __syncthreads();                 // prologue drain: tile 0 resident

#pragma unroll 2
  for (int kt = 0; kt < 16; ++kt) {
    const int cur = kt & 1;
    if (kt + 1 < 16) stage(cur ^ 1, kt + 1);   // prefetch flies during compute

    const char* aB = (const char*)&As[cur][0][0];
    const char* bB = (const char*)&Bs[cur][0][0];
    v8s af[4], bf[4];
#pragma unroll
    for (int mi = 0; mi < 4; ++mi) af[mi] = *(const v8s*)(aB + offA[mi]);
#pragma unroll
    for (int ni = 0; ni < 4; ++ni) bf[ni] = *(const v8s*)(bB + offB[ni]);
#pragma unroll
    for (int mi = 0; mi < 4; ++mi)
#pragma unroll
      for (int ni = 0; ni < 4; ++ni)
        acc[mi][ni] = __builtin_amdgcn_mfma_f32_16x16x32_bf16(af[mi], bf[ni], acc[mi][ni], 0, 0, 0);

    __syncthreads();               // closes reads of cur + drains prefetch
  }

  // Epilogue (verbatim R5): lrelu + Wc2 dot over wave's 64 cols, 16-lane
  // reduce, atomicAdd into FL[m][z].  D-frag: col=l&15, row=(l>>4)*4+reg.
  float bcol[4], wcol[4];
#pragma unroll
  for (int ni = 0; ni < 4; ++ni) {
    int col = bn + wc*64 + ni*16 + fr;
    bcol[ni] = biasz[col];
    wcol[ni] = w2z[col];
  }
#pragma unroll
  for (int mi = 0; mi < 4; ++mi) {
#pragma unroll
    for (int reg = 0; reg < 4; ++reg) {
      float s = 0.f;
#pragma unroll
      for (int ni = 0; ni < 4; ++ni) {
        float v = acc[mi][ni][reg] + bcol[ni];
        v = v >= 0.f ? v : 0.1f * v;
        s += v * wcol[ni];
      }
#pragma unroll
      for (int off = 1; off < 16; off <<= 1)
        s += __shfl_xor(s, off, 64);
      if (fr == 0) {
        int grow = bm + wr*64 + mi*16 + fq*4 + reg;
        atomicAdd(&FL[(size_t)grow * Nq + z], s);
      }
    }
  }
}

// full_out[m][n] = FL[m][n] + bc2[n]; out[b][n] = sigmoid(full_out[n*B+b][n])
__global__ void k_final(const float* __restrict__ fl, const float* __restrict__ bc2,
                        float* __restrict__ out) {
  int i = blockIdx.x * 256 + threadIdx.x;
  int m = i >> 4, n = i & 15;
  float v = fl[i] + bc2[n];
  out[Mq + i] = v;
  if (n == (m >> 10)) {
    int b = m & (Bq - 1);
    out[b * Nq + n] = 1.f / (1.f + __expf(-v));
  }
}

extern "C" void kernel_launch(void* const* d_in, const int* in_sizes, int n_in,
                              void* d_out, int out_size, void* d_ws, size_t ws_size,
                              hipStream_t stream) {
  (void)in_sizes; (void)n_in; (void)out_size; (void)ws_size;
  const float* x   = (const float*)d_in[0];
  const float* Ws1 = (const float*)d_in[1];
  const float* bs1 = (const float*)d_in[2];
  const float* Ws2 = (const float*)d_in[3];
  const float* bs2 = (const float*)d_in[4];
  const float* Wc1 = (const float*)d_in[5];
  const float* bc1 = (const float*)d_in[6];
  const float* Wc2 = (const float*)d_in[7];
  const float* bc2 = (const float*)d_in[8];

  char* ws = (char*)d_ws;
  unsigned short* Xb   = (unsigned short*)(ws);
  unsigned short* Hbuf = (unsigned short*)(ws + (size_t)16*1024*1024);
  unsigned short* Sm   = (unsigned short*)(ws + (size_t)32*1024*1024);
  unsigned short* Ws1t = (unsigned short*)(ws + (size_t)48*1024*1024);
  unsigned short* Ws2t = (unsigned short*)(ws + (size_t)48*1024*1024 + 512*1024);
  unsigned short* Wc1t = (unsigned short*)(ws + (size_t)49*1024*1024);
  float*          FL   = (float*)         (ws + (size_t)57*1024*1024);

  hipMemsetAsync(FL, 0, (size_t)Mq * Nq * sizeof(float), stream);

  k_transpose_x<<<Bq, 256, 0, stream>>>(x, Xb);
  k_transpose_w<<<dim3(16,16,18), dim3(32,8), 0, stream>>>(Ws1, Ws2, Wc1, Ws1t, Ws2t, Wc1t);

  // shared MLP: H = lrelu(Xb@Ws1+bs1); Sm = lrelu(H@Ws2+bs2) in m = n*B+b row order
  k_gemm<0,128><<<dim3(128,4,1), 256, 0, stream>>>(Xb,   Ws1t, bs1, Hbuf, nullptr, 0);
  k_gemm<0,128><<<dim3(128,4,1), 256, 0, stream>>>(Hbuf, Ws2t, bs2, Sm,   nullptr, 1);
  // fused per-head GEMM + H-reduction into FL (m97+dbuf, ~12 waves/CU)
  k_headgemm<<<dim3(128,4,16), 256, 0, stream>>>(Sm, Wc1t, bc1, FL, Wc2);

  k_final<<<(Mq*Nq)/256, 256, 0, stream>>>(FL, bc2, (float*)d_out);
}

// Round 9
// 320.640 us; speedup vs baseline: 1.1063x; 1.0089x over previous
//
#include <hip/hip_runtime.h>
#include <hip/hip_bf16.h>
#include <stdint.h>

// Problem constants
#define Bq 1024
#define Dq 512
#define Nq 16
#define Hq 512
#define Mq (Bq*Nq)   // 16384

typedef short v8s  __attribute__((ext_vector_type(8)));
typedef float v4f  __attribute__((ext_vector_type(4)));
typedef float v16f __attribute__((ext_vector_type(16)));

typedef __attribute__((address_space(3))) unsigned int as3_u32;
typedef __attribute__((address_space(1))) const unsigned int as1_u32;

__device__ __forceinline__ unsigned short f2bf(float f) {
  union { float f; unsigned u; } v; v.f = f;
  return (unsigned short)((v.u + 0x7fffu + ((v.u >> 16) & 1u)) >> 16);
}

// Xb[b*16+n][d] = bf16(x[b][d][n])
__global__ void k_transpose_x(const float* __restrict__ x, unsigned short* __restrict__ xb) {
  __shared__ float lds[Dq][Nq + 1];
  const int b = blockIdx.x;
  const float* xi = x + (size_t)b * Dq * Nq;
  const int t = threadIdx.x;
  for (int p = 0; p < (Dq*Nq)/256; ++p) {
    int i = t + p*256;
    lds[i >> 4][i & (Nq-1)] = xi[i];
  }
  __syncthreads();
  unsigned short* o = xb + (size_t)b * Nq * Dq;
  for (int p = 0; p < (Dq*Nq)/256; ++p) {
    int i = t + p*256;
    o[i] = f2bf(lds[i & (Dq-1)][i >> 9]);   // i = n*512 + d
  }
}

// One dispatch for all weight transposes: z=0 -> Ws1, z=1 -> Ws2, z>=2 -> Wc1[z-2]
__global__ void k_transpose_w(const float* __restrict__ Ws1, const float* __restrict__ Ws2,
                              const float* __restrict__ Wc1,
                              unsigned short* __restrict__ Ws1t, unsigned short* __restrict__ Ws2t,
                              unsigned short* __restrict__ Wc1t) {
  __shared__ float tile[32][33];
  const int z = blockIdx.z;
  const float* in;
  unsigned short* out;
  if (z == 0)      { in = Ws1; out = Ws1t; }
  else if (z == 1) { in = Ws2; out = Ws2t; }
  else             { in = Wc1 + (size_t)(z-2) * 512 * 512; out = Wc1t + (size_t)(z-2) * 512 * 512; }
  const int tx = threadIdx.x, ty = threadIdx.y;  // (32,8)
  const int c0 = blockIdx.x * 32, r0 = blockIdx.y * 32;
#pragma unroll
  for (int j = 0; j < 4; ++j)
    tile[ty + j*8][tx] = in[(size_t)(r0 + ty + j*8) * 512 + c0 + tx];
  __syncthreads();
#pragma unroll
  for (int j = 0; j < 4; ++j) {
    int c = c0 + ty + j*8;   // output row (input col)
    int r = r0 + tx;         // output col (input row)
    out[(size_t)c * 512 + r] = f2bf(tile[tx][ty + j*8]);
  }
}

// ---------------------------------------------------------------------------
// Old-structure GEMM, kept for the two shared-MLP GEMMs (MODE=0 only).
// ---------------------------------------------------------------------------
template<int MODE, int BM>
__global__ __launch_bounds__(256, 2)
void k_gemm(const unsigned short* __restrict__ A,
            const unsigned short* __restrict__ Bt,
            const float* __restrict__ bias,
            void* __restrict__ out_,
            const float* __restrict__ w2,
            int permute) {
  constexpr int BN = 128, BK = 32, KD = 512;
  constexpr int NI = (BM == 256) ? 4 : 2;
  constexpr int AG = BM / 16;
  constexpr int TG = AG + BN / 16;
  __shared__ __align__(16) unsigned short As[2][BM][BK];
  __shared__ __align__(16) unsigned short Bs[2][BN][BK];

  const int t = threadIdx.x;
  const int wave = t >> 6, lane = t & 63;
  const int wr = (BM == 256) ? wave : (wave >> 1);
  const int wc = (BM == 256) ? 0    : (wave & 1);
  const int l32 = lane & 31, kh0 = lane >> 5;
  const int bm = blockIdx.x * BM, bn = blockIdx.y * BN;
  const int z = blockIdx.z;

  const unsigned short* Bz = Bt + (size_t)z * KD * 512;
  const float* biasz = bias + (size_t)z * 512;

  const int lrow = lane >> 2;
  const int lslot = lane & 3;

  auto stage = [&](int buf, int kt) {
#pragma unroll
    for (int i = wave; i < TG; i += 4) {
      const int isA = (i < AG);
      const int r0 = (isA ? i : i - AG) * 16;
      const int row = r0 + lrow;
      const int cg = lslot ^ ((row >> 1) & 3);
      const unsigned short* g = isA ? &A [(size_t)(bm + row) * KD + kt*BK + cg*8]
                                    : &Bz[(size_t)(bn + row) * KD + kt*BK + cg*8];
      as3_u32* d = isA ? (as3_u32*)&As[buf][r0][0] : (as3_u32*)&Bs[buf][r0][0];
      __builtin_amdgcn_global_load_lds((as1_u32*)g, d, 16, 0, 0);
    }
  };

  v16f acc[2][NI] = {};

  stage(0, 0);
  __syncthreads();

  for (int kt = 0; kt < KD / BK; ++kt) {
    const int cur = kt & 1;
    if (kt + 1 < KD / BK) stage(cur ^ 1, kt + 1);

    v8s af[2][2], bf[NI][2];
#pragma unroll
    for (int mi = 0; mi < 2; ++mi) {
      int ra = wr*64 + mi*32 + l32;
#pragma unroll
      for (int kh = 0; kh < 2; ++kh) {
        int c = kh*2 + kh0;
        af[mi][kh] = *(const v8s*)&As[cur][ra][(c ^ ((ra >> 1) & 3)) * 8];
      }
    }
#pragma unroll
    for (int ni = 0; ni < NI; ++ni) {
      int rb = wc*64 + ni*32 + l32;
#pragma unroll
      for (int kh = 0; kh < 2; ++kh) {
        int c = kh*2 + kh0;
        bf[ni][kh] = *(const v8s*)&Bs[cur][rb][(c ^ ((rb >> 1) & 3)) * 8];
      }
    }
#pragma unroll
    for (int kh = 0; kh < 2; ++kh)
#pragma unroll
      for (int mi = 0; mi < 2; ++mi)
#pragma unroll
        for (int ni = 0; ni < NI; ++ni)
          acc[mi][ni] = __builtin_amdgcn_mfma_f32_32x32x16_bf16(af[mi][kh], bf[ni][kh], acc[mi][ni], 0, 0, 0);
    __syncthreads();
  }

  if (MODE == 0) {
    unsigned short* O = (unsigned short*)out_;
#pragma unroll
    for (int mi = 0; mi < 2; ++mi) {
#pragma unroll
      for (int ni = 0; ni < NI; ++ni) {
        int col = bn + wc*64 + ni*32 + l32;
        float bcol = biasz[col];
#pragma unroll
        for (int reg = 0; reg < 16; ++reg) {
          int rl = (reg & 3) + 8*(reg >> 2) + 4*kh0;
          int grow = bm + wr*64 + mi*32 + rl;
          int orow = permute ? ((grow & 15) * Bq + (grow >> 4)) : grow;
          float v = acc[mi][ni][reg] + bcol;
          v = v >= 0.f ? v : 0.1f * v;
          O[(size_t)orow * 512 + col] = f2bf(v);
        }
      }
    }
  } else {
    float* FL = (float*)out_;
    const float* w2z = w2 + (size_t)z * 512;
#pragma unroll
    for (int mi = 0; mi < 2; ++mi) {
#pragma unroll
      for (int reg = 0; reg < 16; ++reg) {
        int rl = (reg & 3) + 8*(reg >> 2) + 4*kh0;
        float s = 0.f;
#pragma unroll
        for (int ni = 0; ni < NI; ++ni) {
          int col = bn + ni*32 + l32;
          float v = acc[mi][ni][reg] + biasz[col];
          v = v >= 0.f ? v : 0.1f * v;
          s += v * w2z[col];
        }
#pragma unroll
        for (int off = 1; off < 32; off <<= 1)
          s += __shfl_xor(s, off, 64);
        if (l32 == 0) {
          int grow = bm + wave*64 + mi*32 + rl;
          atomicAdd(&FL[(size_t)grow * Nq + z], s);
        }
      }
    }
  }
}

// ---------------------------------------------------------------------------
// Head-GEMM v9: 128x256 tile, 256 threads = 4 waves (2x2) of 64x128 each.
// acc[4][8] v4f = 128 regs; per K-step per wave: 12 ds_read_b128 -> 32 MFMA
// (2.67 MFMA/read vs 2.0 in v8; LDS floor 82->62us).  MFMA per barrier-pair
// doubles (128/block-step) and block count halves (4096) -> halves the
// per-block prologue/epilogue/atomic overhead that the R8 post-mortem
// identified as the residual (no pipe >35% busy; occupancy/latency/conflict
// theories all falsified by within-session A/B).  bn splits 4->2: FL atomic
// traffic halves.  Everything else verbatim R8 (passed): zero-conflict
// chunk-XOR swizzle on 64B rows, dbuf with prefetch-before-compute, one
// barrier per K-step, natural dispatch order, 16x16x32 fragments.
// __launch_bounds__(256,2): ~200 unified regs -> 2 blocks/CU (R8 proved
// blocks/CU beyond 2 buys nothing).
// ---------------------------------------------------------------------------
__global__ __launch_bounds__(256, 2)
void k_headgemm(const unsigned short* __restrict__ A,
                const unsigned short* __restrict__ Bt,
                const float* __restrict__ bias,
                float* __restrict__ FL,
                const float* __restrict__ w2) {
  __shared__ __align__(16) unsigned short As[2][128][32];
  __shared__ __align__(16) unsigned short Bs[2][256][32];

  const int t = threadIdx.x;
  const int wave = t >> 6, lane = t & 63;
  const int wr = wave >> 1, wc = wave & 1;         // 2x2 waves of 64x128
  const int fr = lane & 15, fq = lane >> 4;

  const int bm = blockIdx.x * 128;
  const int bn = blockIdx.y * 256;
  const int z  = blockIdx.z;

  const unsigned short* Bz = Bt + (size_t)z * Dq * 512;
  const float* biasz = bias + (size_t)z * 512;
  const float* w2z   = w2   + (size_t)z * 512;

  // Staging (R8-verified lane math for 64B rows): lane l -> row l>>2,
  // 16B slot l&3; source chunk pre-XORed with read swizzle ((row>>1)&3).
  // Per K-step per wave: A rows [wave*32,+32) = 2 issues; B rows
  // [wave*64,+64) = 4 issues; 1 KB (16 rows) per issue.
  const int sr = lane >> 2;
  const int sc = (lane & 3) ^ ((sr >> 1) & 3);
  const unsigned short* aSrc = A  + (size_t)(bm + wave*32 + sr) * Dq + sc*8;
  const unsigned short* bSrc = Bz + (size_t)(bn + wave*64 + sr) * Dq + sc*8;

  auto stage = [&](int buf, int kt) {
#pragma unroll
    for (int j = 0; j < 2; ++j)
      __builtin_amdgcn_global_load_lds((as1_u32*)(aSrc + kt*32 + (size_t)j*16*Dq),
                                       (as3_u32*)&As[buf][wave*32 + j*16][0], 16, 0, 0);
#pragma unroll
    for (int j = 0; j < 4; ++j)
      __builtin_amdgcn_global_load_lds((as1_u32*)(bSrc + kt*32 + (size_t)j*16*Dq),
                                       (as3_u32*)&Bs[buf][wave*64 + j*16][0], 16, 0, 0);
  };

  // Fragment byte offsets (R2/R5/R8-verified formula for 64B rows):
  // row r, lane chunk fq -> LDS chunk fq ^ ((r>>1)&3); (r>>1)&3 == (fr>>1)&3.
  const int swz = (fq ^ ((fr >> 1) & 3)) * 16;
  int offA[4], offB[8];
#pragma unroll
  for (int mi = 0; mi < 4; ++mi) offA[mi] = (wr*64  + mi*16 + fr) * 64 + swz;
#pragma unroll
  for (int ni = 0; ni < 8; ++ni) offB[ni] = (wc*128 + ni*16 + fr) * 64 + swz;

  v4f acc[4][8] = {};

  stage(0, 0);
  __syncthreads();                 // prologue drain: tile 0 resident

  for (int kt = 0; kt < 16; ++kt) {
    const int cur = kt & 1;
    if (kt + 1 < 16) stage(cur ^ 1, kt + 1);   // prefetch flies during compute

    const char* aB = (const char*)&As[cur][0][0];
    const char* bB = (const char*)&Bs[cur][0][0];
    v8s af[4], bf[8];
#pragma unroll
    for (int mi = 0; mi < 4; ++mi) af[mi] = *(const v8s*)(aB + offA[mi]);
#pragma unroll
    for (int ni = 0; ni < 8; ++ni) bf[ni] = *(const v8s*)(bB + offB[ni]);
#pragma unroll
    for (int mi = 0; mi < 4; ++mi)
#pragma unroll
      for (int ni = 0; ni < 8; ++ni)
        acc[mi][ni] = __builtin_amdgcn_mfma_f32_16x16x32_bf16(af[mi], bf[ni], acc[mi][ni], 0, 0, 0);

    __syncthreads();               // closes reads of cur + drains prefetch
  }

  // Epilogue: lrelu + Wc2 dot over this wave's 128 cols, 16-lane reduce,
  // atomicAdd into FL[m][z].  D-frag: col=l&15, row=(l>>4)*4+reg.
  float bcol[8], wcol[8];
#pragma unroll
  for (int ni = 0; ni < 8; ++ni) {
    int col = bn + wc*128 + ni*16 + fr;
    bcol[ni] = biasz[col];
    wcol[ni] = w2z[col];
  }
#pragma unroll
  for (int mi = 0; mi < 4; ++mi) {
#pragma unroll
    for (int reg = 0; reg < 4; ++reg) {
      float s = 0.f;
#pragma unroll
      for (int ni = 0; ni < 8; ++ni) {
        float v = acc[mi][ni][reg] + bcol[ni];
        v = v >= 0.f ? v : 0.1f * v;
        s += v * wcol[ni];
      }
#pragma unroll
      for (int off = 1; off < 16; off <<= 1)
        s += __shfl_xor(s, off, 64);
      if (fr == 0) {
        int grow = bm + wr*64 + mi*16 + fq*4 + reg;
        atomicAdd(&FL[(size_t)grow * Nq + z], s);
      }
    }
  }
}

// full_out[m][n] = FL[m][n] + bc2[n]; out[b][n] = sigmoid(full_out[n*B+b][n])
__global__ void k_final(const float* __restrict__ fl, const float* __restrict__ bc2,
                        float* __restrict__ out) {
  int i = blockIdx.x * 256 + threadIdx.x;
  int m = i >> 4, n = i & 15;
  float v = fl[i] + bc2[n];
  out[Mq + i] = v;
  if (n == (m >> 10)) {
    int b = m & (Bq - 1);
    out[b * Nq + n] = 1.f / (1.f + __expf(-v));
  }
}

extern "C" void kernel_launch(void* const* d_in, const int* in_sizes, int n_in,
                              void* d_out, int out_size, void* d_ws, size_t ws_size,
                              hipStream_t stream) {
  (void)in_sizes; (void)n_in; (void)out_size; (void)ws_size;
  const float* x   = (const float*)d_in[0];
  const float* Ws1 = (const float*)d_in[1];
  const float* bs1 = (const float*)d_in[2];
  const float* Ws2 = (const float*)d_in[3];
  const float* bs2 = (const float*)d_in[4];
  const float* Wc1 = (const float*)d_in[5];
  const float* bc1 = (const float*)d_in[6];
  const float* Wc2 = (const float*)d_in[7];
  const float* bc2 = (const float*)d_in[8];

  char* ws = (char*)d_ws;
  unsigned short* Xb   = (unsigned short*)(ws);
  unsigned short* Hbuf = (unsigned short*)(ws + (size_t)16*1024*1024);
  unsigned short* Sm   = (unsigned short*)(ws + (size_t)32*1024*1024);
  unsigned short* Ws1t = (unsigned short*)(ws + (size_t)48*1024*1024);
  unsigned short* Ws2t = (unsigned short*)(ws + (size_t)48*1024*1024 + 512*1024);
  unsigned short* Wc1t = (unsigned short*)(ws + (size_t)49*1024*1024);
  float*          FL   = (float*)         (ws + (size_t)57*1024*1024);

  hipMemsetAsync(FL, 0, (size_t)Mq * Nq * sizeof(float), stream);

  k_transpose_x<<<Bq, 256, 0, stream>>>(x, Xb);
  k_transpose_w<<<dim3(16,16,18), dim3(32,8), 0, stream>>>(Ws1, Ws2, Wc1, Ws1t, Ws2t, Wc1t);

  // shared MLP: H = lrelu(Xb@Ws1+bs1); Sm = lrelu(H@Ws2+bs2) in m = n*B+b row order
  k_gemm<0,128><<<dim3(128,4,1), 256, 0, stream>>>(Xb,   Ws1t, bs1, Hbuf, nullptr, 0);
  k_gemm<0,128><<<dim3(128,4,1), 256, 0, stream>>>(Hbuf, Ws2t, bs2, Sm,   nullptr, 1);
  // fused per-head GEMM + H-reduction into FL (128x256 wide tile)
  k_headgemm<<<dim3(128,2,16), 256, 0, stream>>>(Sm, Wc1t, bc1, FL, Wc2);

  k_final<<<(Mq*Nq)/256, 256, 0, stream>>>(FL, bc2, (float*)d_out);
}